// Round 6
// baseline (202.194 us; speedup 1.0000x reference)
//
#include <hip/hip_runtime.h>
#include <stdint.h>

// ---------------------------------------------------------------------------
// MultiheadMaskedAttention (B=2, S=2048, H=1024, 16 heads x d=64)
// R15: attn with NO KV LDS staging and NO per-iteration barriers.
// R14 post-mortem: R9/R13/R14 (three different structures) all = 43 µs;
// R12 at 12 waves/CU = 67 µs -> time ~ 1/(waves/CU); no pipe saturated.
// Common factor: barrier-synced LDS staging cadence (vmcnt(0)+s_barrier per
// 64-s tile). But KV is L2-resident (4 heads x 512KB = 2MB per XCD), and
// kb/vtb layouts give MFMA fragments as direct contiguous 16B global loads.
// So: read K and V straight from L2; each wave is an independent dataflow
// pipeline (loads -> QK MFMA -> in-reg softmax -> PV MFMA), no syncs until
// the final 2-wave merge.
//  - Block = one 32-row strip (2 waves: ms=0/1 s-halves). Grid 2048
//    -> 8 blocks/CU, 16 waves/CU, LDS 8.3KB (merge scratch only).
//  - Balance: strip pairs (st, 63-st) -> every CU exactly 132 iterations.
//    Head = bid&31 -> 4 heads per XCD (L2-local KV).
//  - In-register P via pack2 + __builtin_amdgcn_permlane32_swap (R13/R14-
//    harness-verified). Fully-masked half-tiles = shorter trip count.
// GEMMs / prep unchanged.
// ---------------------------------------------------------------------------

typedef __bf16 bf16;
typedef __attribute__((ext_vector_type(8))) __bf16 bf16x8;
typedef __attribute__((ext_vector_type(4))) __bf16 bf16x4;
typedef __attribute__((ext_vector_type(4))) float floatx4;
typedef __attribute__((ext_vector_type(16))) float floatx16;
typedef __attribute__((ext_vector_type(4))) unsigned int uint4v;
typedef __attribute__((ext_vector_type(2))) unsigned int uint2v;

#define SCL 0.18033688011112042f  // (1/sqrt(64)) * log2(e)

__device__ __forceinline__ floatx4 mfma_bf16(bf16x8 a, bf16x8 b, floatx4 c) {
  return __builtin_amdgcn_mfma_f32_16x16x32_bf16(a, b, c, 0, 0, 0);
}

// 32x32x16: A lane l holds m=l&31, k=(l>>5)*8+j ; B: n=l&31, k=(l>>5)*8+j ;
// D: n=lane&31, m=(reg&3)+8*(reg>>2)+4*(lane>>5)  [verified m74/m101, R12]
__device__ __forceinline__ floatx16 mfma32(bf16x8 a, bf16x8 b, floatx16 c) {
  return __builtin_amdgcn_mfma_f32_32x32x16_bf16(a, b, c, 0, 0, 0);
}

__device__ __forceinline__ void cp_g2l_16(const bf16* g, bf16* l) {
  // async global->LDS, 16B/lane; LDS dest = wave-uniform base + lane*16
  __builtin_amdgcn_global_load_lds(
      (const __attribute__((address_space(1))) void*)g,
      (__attribute__((address_space(3))) void*)l, 16, 0, 0);
}

__device__ __forceinline__ floatx16 zero16() {
  floatx16 z;
#pragma unroll
  for (int i = 0; i < 16; ++i) z[i] = 0.f;
  return z;
}

// two f32 -> one u32 of 2 bf16 (compiler emits cvt_pk; don't hand-write, m240)
__device__ __forceinline__ uint32_t pack2(float lo, float hi2) {
  union { bf16 h[2]; uint32_t u; } x;
  x.h[0] = (bf16)lo; x.h[1] = (bf16)hi2;
  return x.u;
}

// new_a = {a_lo, b_lo}, new_b = {a_hi, b_hi} across the lane<32 / lane>=32 halves
__device__ __forceinline__ uint2v permswap(uint32_t a, uint32_t b) {
  return __builtin_amdgcn_permlane32_swap(a, b, false, false);
}

__device__ __forceinline__ bf16x8 mk_pf(uint32_t w0, uint32_t w1, uint32_t w2,
                                        uint32_t w3) {
  union { uint4v u; bf16x8 v; } c;
  c.u = (uint4v){w0, w1, w2, w3};
  return c.v;
}

// ---- merged prep: cast x -> bf16 ; cast+transpose w_qkv, w_o ----
__global__ __launch_bounds__(256) void prep_kernel(
    const float* __restrict__ x, bf16* __restrict__ xb,
    const float* __restrict__ w_qkv, bf16* __restrict__ wqkvt,
    const float* __restrict__ w_o, bf16* __restrict__ wot) {
  const int b = blockIdx.x;
  const int tid = threadIdx.x;
  if (b < 4096) {
    const int i = (b * 256 + tid) * 4;
    floatx4 v = *(const floatx4*)(x + i);
    bf16x4 o;
    o[0] = (bf16)v[0]; o[1] = (bf16)v[1]; o[2] = (bf16)v[2]; o[3] = (bf16)v[3];
    *(bf16x4*)(xb + i) = o;
    return;
  }
  __shared__ float tile[32][33];
  const float* W; bf16* Wt; int K, N, n0, k0;
  if (b < 7168) {
    const int bb = b - 4096;
    W = w_qkv; Wt = wqkvt; K = 1024; N = 3072;
    n0 = (bb % 96) * 32; k0 = (bb / 96) * 32;
  } else {
    const int bb = b - 7168;
    W = w_o; Wt = wot; K = 1024; N = 1024;
    n0 = (bb & 31) * 32; k0 = (bb >> 5) * 32;
  }
  const int tx = tid & 31, ty = tid >> 5;
  for (int i = 0; i < 4; ++i)
    tile[ty + 8 * i][tx] = W[(size_t)(k0 + ty + 8 * i) * N + n0 + tx];
  __syncthreads();
  for (int i = 0; i < 4; ++i)
    Wt[(size_t)(n0 + ty + 8 * i) * K + k0 + tx] = (bf16)tile[tx][ty + 8 * i];
}

// ---- GEMM: C = A(M x K bf16 rm) * Bt(N x K bf16 rm)^T + bias ----
template <int MODE, int MI>
__global__ __launch_bounds__(256, 3) void gemm_bt_kernel(
    const bf16* __restrict__ A, const bf16* __restrict__ Bt,
    const float* __restrict__ bias, float* __restrict__ outF,
    bf16* __restrict__ qb, bf16* __restrict__ kb, bf16* __restrict__ vtb,
    int N, int K) {
  constexpr int BM = MI * 32;
  __shared__ bf16 As[BM * 32];
  __shared__ bf16 Bs[128 * 32];
  const int tid = threadIdx.x;
  const int w = tid >> 6, lane = tid & 63;
  const int l16 = lane & 15, quad = lane >> 4;
  const int m0 = blockIdx.y * BM, n0 = blockIdx.x * 128;
  const int wm = (w & 1) * (BM / 2), wn = (w >> 1) * 64;

  const int arow = w * (BM / 4) + (lane >> 2);
  const int acol = (lane & 3) * 8;
  const bf16* Ag = A + (size_t)(m0 + arow) * K + acol;
  bf16* Al = As + arow * 32 + acol;
  const int brow = w * 32 + (lane >> 2);
  const bf16* Bg = Bt + (size_t)(n0 + brow) * K + acol;
  bf16* Bl = Bs + brow * 32 + acol;

  floatx4 acc[MI][4];
#pragma unroll
  for (int i = 0; i < MI; ++i)
#pragma unroll
    for (int j = 0; j < 4; ++j) acc[i][j] = (floatx4){0.f, 0.f, 0.f, 0.f};

  for (int k0 = 0; k0 < K; k0 += 32) {
    __syncthreads();
    cp_g2l_16(Ag + k0, Al);
    if (MI == 4) cp_g2l_16(Ag + (size_t)16 * K + k0, Al + 16 * 32);
    cp_g2l_16(Bg + k0, Bl);
    cp_g2l_16(Bg + (size_t)16 * K + k0, Bl + 16 * 32);
    __syncthreads();
    bf16x8 af[MI], bfr[4];
#pragma unroll
    for (int i = 0; i < MI; ++i)
      af[i] = *(const bf16x8*)(&As[(wm + i * 16 + l16) * 32 + quad * 8]);
#pragma unroll
    for (int j = 0; j < 4; ++j)
      bfr[j] = *(const bf16x8*)(&Bs[(wn + j * 16 + l16) * 32 + quad * 8]);
#pragma unroll
    for (int i = 0; i < MI; ++i)
#pragma unroll
      for (int j = 0; j < 4; ++j)
        acc[i][j] = mfma_bf16(af[i], bfr[j], acc[i][j]);
  }

#pragma unroll
  for (int i = 0; i < MI; ++i)
#pragma unroll
    for (int j = 0; j < 4; ++j) {
      const int nn = n0 + wn + j * 16 + l16;
      const float bv = bias[nn];
      const int mbase = m0 + wm + i * 16 + quad * 4;
      if (MODE == 1) {
#pragma unroll
        for (int r = 0; r < 4; ++r)
          outF[(size_t)(mbase + r) * N + nn] = acc[i][j][r] + bv;
      } else {
        const int which = nn >> 10;  // uniform per block
        const int rem = nn & 1023;
        const int h = rem >> 6, d = rem & 63;
        const int b = mbase >> 11, s = mbase & 2047;
        const size_t bh = (size_t)(b * 16 + h);
        if (which == 2) {
          bf16x4 pk;
#pragma unroll
          for (int r = 0; r < 4; ++r) pk[r] = (bf16)(acc[i][j][r] + bv);
          *(bf16x4*)(vtb + (bh * 64 + d) * 2048 + s) = pk;
        } else if (which == 0) {
#pragma unroll
          for (int r = 0; r < 4; ++r)
            qb[(bh * 2048 + s + r) * 64 + d] = (bf16)((acc[i][j][r] + bv) * SCL);
        } else {
#pragma unroll
          for (int r = 0; r < 4; ++r)
            kb[(bh * 2048 + s + r) * 64 + d] = (bf16)(acc[i][j][r] + bv);
        }
      }
    }
}

// ---- Flash attention, causal. 2048 blocks x 128 threads (2 waves). ------
// Block = one 32-row strip st of head bh. Wave ms handles the ms-th 32-s
// half of each 64-s tile. K/V read directly from global (L2-resident);
// no LDS staging, no per-iteration barriers. Final ms0+ms1 merge via LDS.
__global__ __launch_bounds__(128, 4) void attn_kernel(
    const bf16* __restrict__ Qb, const bf16* __restrict__ Kb,
    const bf16* __restrict__ Vtb, bf16* __restrict__ attnb) {
  __shared__ float fO[2048];  // [ql 0..31][d 0..63]
  __shared__ float fL[32];
  const int bid = blockIdx.x;
  const int c = bid & 255, qq = bid >> 8;
  const int bh = c & 31;  // head: 4 heads per XCD (bid%8 = bh%8)
  const int kk = c >> 5;  // 0..7
  // co-resident stride-256 columns: strips {kk*4+j, 63-(kk*4+j)} j=0..3
  // -> every CU totals 132 tile-iterations.
  const int st = (qq < 4) ? (kk * 4 + qq) : (63 - (kk * 4 + qq - 4));
  const int tid = threadIdx.x;
  const int ms = tid >> 6, lane = tid & 63;
  const int l31 = lane & 31, hi = lane >> 5;
  const int q0s = st * 32;  // this strip's 32 q-rows
  const int b = bh >> 4, h = bh & 15;
  const int g = st >> 1;  // diagonal tile index
  // even strips: ms=1 half of the diagonal tile is fully masked -> skip it
  const int myNt = ((st & 1) == 0 && ms == 1) ? g : g + 1;

  const bf16* Qh = Qb + (size_t)bh * 2048 * 64;
  const bf16* Kh = Kb + (size_t)bh * 2048 * 64;
  const bf16* Vh = Vtb + (size_t)bh * 64 * 2048;

  // Q B-frags: n=q=q0s+l31, k=d=kd*16+hi*8+j
  bf16x8 qf[4];
  {
    const bf16* Qr = Qh + (size_t)(q0s + l31) * 64 + hi * 8;
#pragma unroll
    for (int kd = 0; kd < 4; ++kd) qf[kd] = *(const bf16x8*)(Qr + kd * 16);
  }
  bf16x8 ones;
#pragma unroll
  for (int j = 0; j < 8; ++j) ones[j] = (bf16)1.0f;

  floatx16 O0 = zero16(), O1 = zero16(), Ol = zero16();

  // loop-invariant lane base pointers
  // K A-frag row: s = t*64 + ms*32 + l31 ; d-chunk kd*16 + hi*8
  const bf16* Kr = Kh + (size_t)(ms * 32 + l31) * 64 + hi * 8;
  // V B-frag row: d = l31 (O0) / 32+l31 (O1); s-chunk = t*64 + ms*32 (+16) + hi*8
  const bf16* Vr0 = Vh + (size_t)l31 * 2048 + ms * 32 + hi * 8;
  const bf16* Vr1 = Vr0 + (size_t)32 * 2048;

  for (int t = 0; t < myNt; ++t) {
    const bool diag = (t == g);

    // K fragments for this wave's 32 s-rows (4 x b128 global, L2-hit)
    const bf16* Kt = Kr + (size_t)t * 4096;
    bf16x8 kf0 = *(const bf16x8*)(Kt);
    bf16x8 kf1 = *(const bf16x8*)(Kt + 16);
    bf16x8 kf2 = *(const bf16x8*)(Kt + 32);
    bf16x8 kf3 = *(const bf16x8*)(Kt + 48);

    // V fragments (independent of QK; issued early)
    bf16x8 va0 = *(const bf16x8*)(Vr0 + t * 64);
    bf16x8 va1 = *(const bf16x8*)(Vr1 + t * 64);
    bf16x8 vb0 = *(const bf16x8*)(Vr0 + t * 64 + 16);
    bf16x8 vb1 = *(const bf16x8*)(Vr1 + t * 64 + 16);

    // S^T = K*Q^T : 4 chained MFMAs over d
    floatx16 sf = zero16();
    sf = mfma32(kf0, qf[0], sf);
    sf = mfma32(kf1, qf[1], sf);
    sf = mfma32(kf2, qf[2], sf);
    sf = mfma32(kf3, qf[3], sf);

    // mask -> exp2
    float e[16];
#pragma unroll
    for (int r = 0; r < 16; ++r) {
      float s = sf[r];
      if (diag) {
        const int kc = t * 64 + ms * 32 + (r & 3) + 8 * (r >> 2) + 4 * hi;
        s = (kc <= q0s + l31) ? s : -1e30f;
      }
      e[r] = __builtin_amdgcn_exp2f(s);
    }

    // in-register P: pack bf16 pairs, swap halves across lane<32/lane>=32
    uint32_t W[8];
#pragma unroll
    for (int i = 0; i < 8; ++i) W[i] = pack2(e[2 * i], e[2 * i + 1]);
    uint2v s0 = permswap(W[0], W[2]);
    uint2v s1 = permswap(W[1], W[3]);
    bf16x8 pa = mk_pf(s0.x, s1.x, s0.y, s1.y);
    uint2v s2 = permswap(W[4], W[6]);
    uint2v s3 = permswap(W[5], W[7]);
    bf16x8 pb = mk_pf(s2.x, s3.x, s2.y, s3.y);

    // O[q][d] += P V ; l[q] += P * 1
    O0 = mfma32(pa, va0, O0);
    O1 = mfma32(pa, va1, O1);
    Ol = mfma32(pa, ones, Ol);
    O0 = mfma32(pb, vb0, O0);
    O1 = mfma32(pb, vb1, O1);
    Ol = mfma32(pb, ones, Ol);
  }

  // merge ms halves: ms=1 -> LDS, ms=0 adds and writes out.
  __syncthreads();
  if (ms == 1) {
#pragma unroll
    for (int r = 0; r < 16; ++r) {
      const int ql = (r & 3) + 8 * (r >> 2) + 4 * hi;
      fO[ql * 64 + l31] = O0[r];
      fO[ql * 64 + 32 + l31] = O1[r];
      if (l31 == 0) fL[ql] = Ol[r];
    }
  }
  __syncthreads();
  if (ms == 0) {
#pragma unroll
    for (int r = 0; r < 16; ++r) {
      const int ql = (r & 3) + 8 * (r >> 2) + 4 * hi;
      const float o0 = O0[r] + fO[ql * 64 + l31];
      const float o1 = O1[r] + fO[ql * 64 + 32 + l31];
      const float inv = 1.f / (Ol[r] + fL[ql]);
      bf16* dst = attnb + ((size_t)(b * 2048 + q0s + ql)) * 1024 + h * 64;
      dst[l31] = (bf16)(o0 * inv);
      dst[32 + l31] = (bf16)(o1 * inv);
    }
  }
}

// ---------------------------------------------------------------------------
extern "C" void kernel_launch(void* const* d_in, const int* in_sizes, int n_in,
                              void* d_out, int out_size, void* d_ws, size_t ws_size,
                              hipStream_t stream) {
  const float* x     = (const float*)d_in[0];  // (2,2048,1024)
  const float* w_qkv = (const float*)d_in[1];  // (1024,3072)
  const float* b_qkv = (const float*)d_in[2];  // (3072)
  const float* w_o   = (const float*)d_in[3];  // (1024,1024)
  const float* b_o   = (const float*)d_in[4];  // (1024)
  float* out = (float*)d_out;                  // (2,2048,1024) fp32

  char* ws = (char*)d_ws;
  bf16* xb    = (bf16*)ws; ws += (size_t)4096 * 1024 * 2;
  bf16* wqkvt = (bf16*)ws; ws += (size_t)3072 * 1024 * 2;
  bf16* wot   = (bf16*)ws; ws += (size_t)1024 * 1024 * 2;
  bf16* qb    = (bf16*)ws; ws += (size_t)32 * 2048 * 64 * 2;
  bf16* kb    = (bf16*)ws; ws += (size_t)32 * 2048 * 64 * 2;
  bf16* vtb   = (bf16*)ws; ws += (size_t)32 * 2048 * 64 * 2;  // (bh,64,S)
  bf16* attnb = (bf16*)ws; ws += (size_t)4096 * 1024 * 2;

  prep_kernel<<<8192, 256, 0, stream>>>(x, xb, w_qkv, wqkvt, w_o, wot);
  gemm_bt_kernel<0, 4><<<dim3(24, 32), 256, 0, stream>>>(
      xb, wqkvt, b_qkv, nullptr, qb, kb, vtb, 3072, 1024);
  attn_kernel<<<2048, 128, 0, stream>>>(qb, kb, vtb, attnb);
  gemm_bt_kernel<1, 2><<<dim3(8, 64), 256, 0, stream>>>(
      attnb, wot, b_o, out, nullptr, nullptr, nullptr, 1024, 1024);
}

// Round 7
// 170.859 us; speedup vs baseline: 1.1834x; 1.1834x over previous
//
#include <hip/hip_runtime.h>
#include <stdint.h>

// ---------------------------------------------------------------------------
// MultiheadMaskedAttention (B=2, S=2048, H=1024, 16 heads x d=64)
// R16: R13's verified structure + counted-vmcnt staging pipeline (T3/T4).
// Diagnosis: R9/R13/R14 all pinned at ~1560 cyc/block-iteration; per-SIMD
// issue work only ~330 cyc; R15 (unstaged) ~2500 cyc/wave-iter. Consistent
// explanation: effective L2 latency under load ~1500-2000 cyc, and
// __syncthreads() per iteration = s_waitcnt vmcnt(0) + s_barrier -> full
// staging-queue drain every tile (the m97 barrier-drain mechanism).
// Fix: K 3-deep (prefetch distance 2), V 2-deep (distance 1; V needed only
// at PV), raw s_barrier with NO drain at loop top, single mid-iteration
// s_waitcnt vmcnt(4) (leaves K(t+2),V(t+1) in flight; proves K(t+1),V(t)
// complete). Tail keeps counts uniform via clamped-source dummy stages into
// dead buffers. T5 setprio around MFMA clusters.
// LDS 3*8K + 2*8K = 40960 -> 4 blocks/CU = 16 waves/CU.
// Math/merge identical to R13 (harness-verified). GEMMs / prep unchanged.
// ---------------------------------------------------------------------------

typedef __bf16 bf16;
typedef __attribute__((ext_vector_type(8))) __bf16 bf16x8;
typedef __attribute__((ext_vector_type(4))) __bf16 bf16x4;
typedef __attribute__((ext_vector_type(4))) float floatx4;
typedef __attribute__((ext_vector_type(16))) float floatx16;
typedef __attribute__((ext_vector_type(4))) unsigned int uint4v;
typedef __attribute__((ext_vector_type(2))) unsigned int uint2v;

#define SCL 0.18033688011112042f  // (1/sqrt(64)) * log2(e)

__device__ __forceinline__ floatx4 mfma_bf16(bf16x8 a, bf16x8 b, floatx4 c) {
  return __builtin_amdgcn_mfma_f32_16x16x32_bf16(a, b, c, 0, 0, 0);
}

// 32x32x16: A lane l holds m=l&31, k=(l>>5)*8+j ; B: n=l&31, k=(l>>5)*8+j ;
// D: n=lane&31, m=(reg&3)+8*(reg>>2)+4*(lane>>5)  [verified m74/m101, R12]
__device__ __forceinline__ floatx16 mfma32(bf16x8 a, bf16x8 b, floatx16 c) {
  return __builtin_amdgcn_mfma_f32_32x32x16_bf16(a, b, c, 0, 0, 0);
}

__device__ __forceinline__ void cp_g2l_16(const bf16* g, bf16* l) {
  // async global->LDS, 16B/lane; LDS dest = wave-uniform base + lane*16
  __builtin_amdgcn_global_load_lds(
      (const __attribute__((address_space(1))) void*)g,
      (__attribute__((address_space(3))) void*)l, 16, 0, 0);
}

__device__ __forceinline__ floatx16 zero16() {
  floatx16 z;
#pragma unroll
  for (int i = 0; i < 16; ++i) z[i] = 0.f;
  return z;
}

// two f32 -> one u32 of 2 bf16 (compiler emits cvt_pk; don't hand-write, m240)
__device__ __forceinline__ uint32_t pack2(float lo, float hi2) {
  union { bf16 h[2]; uint32_t u; } x;
  x.h[0] = (bf16)lo; x.h[1] = (bf16)hi2;
  return x.u;
}

// new_a = {a_lo, b_lo}, new_b = {a_hi, b_hi} across the lane<32 / lane>=32 halves
__device__ __forceinline__ uint2v permswap(uint32_t a, uint32_t b) {
  return __builtin_amdgcn_permlane32_swap(a, b, false, false);
}

__device__ __forceinline__ bf16x8 mk_pf(uint32_t w0, uint32_t w1, uint32_t w2,
                                        uint32_t w3) {
  union { uint4v u; bf16x8 v; } c;
  c.u = (uint4v){w0, w1, w2, w3};
  return c.v;
}

// ---- merged prep: cast x -> bf16 ; cast+transpose w_qkv, w_o ----
__global__ __launch_bounds__(256) void prep_kernel(
    const float* __restrict__ x, bf16* __restrict__ xb,
    const float* __restrict__ w_qkv, bf16* __restrict__ wqkvt,
    const float* __restrict__ w_o, bf16* __restrict__ wot) {
  const int b = blockIdx.x;
  const int tid = threadIdx.x;
  if (b < 4096) {
    const int i = (b * 256 + tid) * 4;
    floatx4 v = *(const floatx4*)(x + i);
    bf16x4 o;
    o[0] = (bf16)v[0]; o[1] = (bf16)v[1]; o[2] = (bf16)v[2]; o[3] = (bf16)v[3];
    *(bf16x4*)(xb + i) = o;
    return;
  }
  __shared__ float tile[32][33];
  const float* W; bf16* Wt; int K, N, n0, k0;
  if (b < 7168) {
    const int bb = b - 4096;
    W = w_qkv; Wt = wqkvt; K = 1024; N = 3072;
    n0 = (bb % 96) * 32; k0 = (bb / 96) * 32;
  } else {
    const int bb = b - 7168;
    W = w_o; Wt = wot; K = 1024; N = 1024;
    n0 = (bb & 31) * 32; k0 = (bb >> 5) * 32;
  }
  const int tx = tid & 31, ty = tid >> 5;
  for (int i = 0; i < 4; ++i)
    tile[ty + 8 * i][tx] = W[(size_t)(k0 + ty + 8 * i) * N + n0 + tx];
  __syncthreads();
  for (int i = 0; i < 4; ++i)
    Wt[(size_t)(n0 + ty + 8 * i) * K + k0 + tx] = (bf16)tile[tx][ty + 8 * i];
}

// ---- GEMM: C = A(M x K bf16 rm) * Bt(N x K bf16 rm)^T + bias ----
template <int MODE, int MI>
__global__ __launch_bounds__(256, 3) void gemm_bt_kernel(
    const bf16* __restrict__ A, const bf16* __restrict__ Bt,
    const float* __restrict__ bias, float* __restrict__ outF,
    bf16* __restrict__ qb, bf16* __restrict__ kb, bf16* __restrict__ vtb,
    int N, int K) {
  constexpr int BM = MI * 32;
  __shared__ bf16 As[BM * 32];
  __shared__ bf16 Bs[128 * 32];
  const int tid = threadIdx.x;
  const int w = tid >> 6, lane = tid & 63;
  const int l16 = lane & 15, quad = lane >> 4;
  const int m0 = blockIdx.y * BM, n0 = blockIdx.x * 128;
  const int wm = (w & 1) * (BM / 2), wn = (w >> 1) * 64;

  const int arow = w * (BM / 4) + (lane >> 2);
  const int acol = (lane & 3) * 8;
  const bf16* Ag = A + (size_t)(m0 + arow) * K + acol;
  bf16* Al = As + arow * 32 + acol;
  const int brow = w * 32 + (lane >> 2);
  const bf16* Bg = Bt + (size_t)(n0 + brow) * K + acol;
  bf16* Bl = Bs + brow * 32 + acol;

  floatx4 acc[MI][4];
#pragma unroll
  for (int i = 0; i < MI; ++i)
#pragma unroll
    for (int j = 0; j < 4; ++j) acc[i][j] = (floatx4){0.f, 0.f, 0.f, 0.f};

  for (int k0 = 0; k0 < K; k0 += 32) {
    __syncthreads();
    cp_g2l_16(Ag + k0, Al);
    if (MI == 4) cp_g2l_16(Ag + (size_t)16 * K + k0, Al + 16 * 32);
    cp_g2l_16(Bg + k0, Bl);
    cp_g2l_16(Bg + (size_t)16 * K + k0, Bl + 16 * 32);
    __syncthreads();
    bf16x8 af[MI], bfr[4];
#pragma unroll
    for (int i = 0; i < MI; ++i)
      af[i] = *(const bf16x8*)(&As[(wm + i * 16 + l16) * 32 + quad * 8]);
#pragma unroll
    for (int j = 0; j < 4; ++j)
      bfr[j] = *(const bf16x8*)(&Bs[(wn + j * 16 + l16) * 32 + quad * 8]);
#pragma unroll
    for (int i = 0; i < MI; ++i)
#pragma unroll
      for (int j = 0; j < 4; ++j)
        acc[i][j] = mfma_bf16(af[i], bfr[j], acc[i][j]);
  }

#pragma unroll
  for (int i = 0; i < MI; ++i)
#pragma unroll
    for (int j = 0; j < 4; ++j) {
      const int nn = n0 + wn + j * 16 + l16;
      const float bv = bias[nn];
      const int mbase = m0 + wm + i * 16 + quad * 4;
      if (MODE == 1) {
#pragma unroll
        for (int r = 0; r < 4; ++r)
          outF[(size_t)(mbase + r) * N + nn] = acc[i][j][r] + bv;
      } else {
        const int which = nn >> 10;  // uniform per block
        const int rem = nn & 1023;
        const int h = rem >> 6, d = rem & 63;
        const int b = mbase >> 11, s = mbase & 2047;
        const size_t bh = (size_t)(b * 16 + h);
        if (which == 2) {
          bf16x4 pk;
#pragma unroll
          for (int r = 0; r < 4; ++r) pk[r] = (bf16)(acc[i][j][r] + bv);
          *(bf16x4*)(vtb + (bh * 64 + d) * 2048 + s) = pk;
        } else if (which == 0) {
#pragma unroll
          for (int r = 0; r < 4; ++r)
            qb[(bh * 2048 + s + r) * 64 + d] = (bf16)((acc[i][j][r] + bv) * SCL);
        } else {
#pragma unroll
          for (int r = 0; r < 4; ++r)
            kb[(bh * 2048 + s + r) * 64 + d] = (bf16)(acc[i][j][r] + bv);
        }
      }
    }
}

// ---- Flash attention, causal. 1024 blocks x 256 threads (4 waves). ------
// Block = one 64-row q-group g of one head. Wave w: strip=(w>>1), ms=(w&1).
// K 3-deep LDS (prefetch distance 2), V 2-deep (distance 1). Raw s_barrier
// at loop top (no vmcnt drain); one mid-iteration s_waitcnt vmcnt(4).
__global__ __launch_bounds__(256, 4) void attn_kernel(
    const bf16* __restrict__ Qb, const bf16* __restrict__ Kb,
    const bf16* __restrict__ Vtb, bf16* __restrict__ attnb) {
  __shared__ bf16 Ks[3][4096];  // [buf][64 s-rows x 64 d] swizzled chunks
  __shared__ bf16 Vs[2][4096];  // [buf][64 d-rows x 64 s] swizzled chunks
  const int bid = blockIdx.x;
  const int c = bid & 255, qq = bid >> 8;
  const int bh = c & 31;        // head: all 32 blocks of a head on one XCD
  const int kk = c >> 5;        // 0..7
  // stride-256 columns get groups {k, 31-k, 8+k, 23-k}: 66 iters/column
  const int g = (qq == 0) ? kk : (qq == 1) ? 31 - kk
              : (qq == 2) ? 8 + kk : 23 - kk;
  const int tid = threadIdx.x;
  const int w = tid >> 6, lane = tid & 63;
  const int l31 = lane & 31, hi = lane >> 5;
  const int strip = w >> 1, ms = w & 1;
  const int q0s = g * 64 + strip * 32;  // this wave's 32 q-rows
  const int b = bh >> 4, h = bh & 15;
  const int nt = g + 1;

  const bf16* Qh = Qb + (size_t)bh * 2048 * 64;
  const bf16* Kh = Kb + (size_t)bh * 2048 * 64;
  const bf16* Vh = Vtb + (size_t)bh * 64 * 2048;

  // staging: thread stages chunks {tid, tid+256} of K and of V (16B each).
  // dest chunk c: row=c>>3, slot=c&7 holds source chunk (slot-row)&7
  const int c0 = tid, c1 = tid + 256;
  const int kof0 = (c0 >> 3) * 64 + ((((c0 & 7) - (c0 >> 3)) & 7) * 8);
  const int kof1 = (c1 >> 3) * 64 + ((((c1 & 7) - (c1 >> 3)) & 7) * 8);
  const int vof0 = (c0 >> 3) * 2048 + ((((c0 & 7) - (c0 >> 3)) & 7) * 8);
  const int vof1 = (c1 >> 3) * 2048 + ((((c1 & 7) - (c1 >> 3)) & 7) * 8);

  // Q B-frags: n=q=q0s+l31, k=d=kd*16+hi*8+j
  bf16x8 qf[4];
  {
    const bf16* Qr = Qh + (size_t)(q0s + l31) * 64 + hi * 8;
#pragma unroll
    for (int kd = 0; kd < 4; ++kd) qf[kd] = *(const bf16x8*)(Qr + kd * 16);
  }
  bf16x8 ones;
#pragma unroll
  for (int j = 0; j < 8; ++j) ones[j] = (bf16)1.0f;

  floatx16 O0 = zero16(), O1 = zero16(), Ol = zero16();

  // prologue: K(0)->Kb0, K(1 or clamp)->Kb1, V(0)->Vb0 ; keep K1,V0 in flight
  {
    const int k1 = (1 < nt) ? 1 : 0;
    cp_g2l_16(Kh + kof0, &Ks[0][c0 * 8]);
    cp_g2l_16(Kh + kof1, &Ks[0][c1 * 8]);
    cp_g2l_16(Kh + (size_t)k1 * 4096 + kof0, &Ks[1][c0 * 8]);
    cp_g2l_16(Kh + (size_t)k1 * 4096 + kof1, &Ks[1][c1 * 8]);
    cp_g2l_16(Vh + vof0, &Vs[0][c0 * 8]);
    cp_g2l_16(Vh + vof1, &Vs[0][c1 * 8]);
    asm volatile("s_waitcnt vmcnt(4)" ::: "memory");  // K(0) staged
    __builtin_amdgcn_sched_barrier(0);
  }

  int kr = 0;  // K read buffer = t % 3
  for (int t = 0; t < nt; ++t) {
    // all waves: K(t) visible (issuer drained at its mid-(t-1) vmcnt(4));
    // buffers being overwritten below were fully read during t-1.
    __builtin_amdgcn_s_barrier();
    __builtin_amdgcn_sched_barrier(0);

    // issue staging: K(t+2)->Kb[(t+2)%3], V(t+1)->Vb[(t+1)&1].
    // Tail: clamped source (tile 0) into the (dead) dest keeps vmcnt uniform.
    {
      const int tk = (t + 2 < nt) ? t + 2 : 0;
      const int tv = (t + 1 < nt) ? t + 1 : 0;
      const int kst = (kr >= 1) ? kr - 1 : 2;  // (t+2)%3
      cp_g2l_16(Kh + (size_t)tk * 4096 + kof0, &Ks[kst][c0 * 8]);
      cp_g2l_16(Kh + (size_t)tk * 4096 + kof1, &Ks[kst][c1 * 8]);
      cp_g2l_16(Vh + (size_t)tv * 64 + vof0, &Vs[(t + 1) & 1][c0 * 8]);
      cp_g2l_16(Vh + (size_t)tv * 64 + vof1, &Vs[(t + 1) & 1][c1 * 8]);
    }

    const bool diag = (t == g);
    if (!(diag && strip == 0 && ms == 1)) {  // skip fully-masked half-tile
      const bf16* KsC = &Ks[kr][0];

      // S^T = K*Q^T over this wave's 32 s-rows: 4 chained MFMAs over d
      floatx16 sf = zero16();
      const int row = ms * 32 + l31;
      __builtin_amdgcn_s_setprio(1);
#pragma unroll
      for (int kd = 0; kd < 4; ++kd) {
        bf16x8 kf = *(const bf16x8*)(
            &KsC[row * 64 + (((kd * 2 + hi) + row) & 7) * 8]);
        sf = mfma32(kf, qf[kd], sf);
      }
      __builtin_amdgcn_s_setprio(0);

      // mask -> exp2
      float e[16];
#pragma unroll
      for (int r = 0; r < 16; ++r) {
        float s = sf[r];
        if (diag) {
          const int kc = t * 64 + ms * 32 + (r & 3) + 8 * (r >> 2) + 4 * hi;
          s = (kc <= q0s + l31) ? s : -1e30f;
        }
        e[r] = __builtin_amdgcn_exp2f(s);
      }

      // in-register P: pack bf16 pairs, swap halves across lane<32/lane>=32
      uint32_t W[8];
#pragma unroll
      for (int i = 0; i < 8; ++i) W[i] = pack2(e[2 * i], e[2 * i + 1]);
      uint2v s0 = permswap(W[0], W[2]);
      uint2v s1 = permswap(W[1], W[3]);
      bf16x8 pa = mk_pf(s0.x, s1.x, s0.y, s1.y);
      uint2v s2 = permswap(W[4], W[6]);
      uint2v s3 = permswap(W[5], W[7]);
      bf16x8 pb = mk_pf(s2.x, s3.x, s2.y, s3.y);

      // V(t) staged (drains K(t+1),V(t); leaves K(t+2),V(t+1) in flight)
      asm volatile("s_waitcnt vmcnt(4)" ::: "memory");
      __builtin_amdgcn_sched_barrier(0);

      const bf16* VsC = &Vs[t & 1][0];
      const int ksA = ms * 2, ksB = ms * 2 + 1;
      const int r0 = l31, r1 = 32 + l31;
      bf16x8 va0 = *(const bf16x8*)(&VsC[r0 * 64 + (((ksA * 2 + hi) + r0) & 7) * 8]);
      bf16x8 va1 = *(const bf16x8*)(&VsC[r1 * 64 + (((ksA * 2 + hi) + r1) & 7) * 8]);
      bf16x8 vb0 = *(const bf16x8*)(&VsC[r0 * 64 + (((ksB * 2 + hi) + r0) & 7) * 8]);
      bf16x8 vb1 = *(const bf16x8*)(&VsC[r1 * 64 + (((ksB * 2 + hi) + r1) & 7) * 8]);

      __builtin_amdgcn_s_setprio(1);
      O0 = mfma32(pa, va0, O0);
      O1 = mfma32(pa, va1, O1);
      Ol = mfma32(pa, ones, Ol);
      O0 = mfma32(pb, vb0, O0);
      O1 = mfma32(pb, vb1, O1);
      Ol = mfma32(pb, ones, Ol);
      __builtin_amdgcn_s_setprio(0);
    }
    kr = (kr == 2) ? 0 : kr + 1;
  }

  // merge ms halves (R13-verified layout): full drain once, reuse LDS.
  __syncthreads();
  float* fO = (float*)(&Ks[0][0]);  // [strip][ql][d] = 4096 floats (16KB)
  float* fL = (float*)(&Vs[0][0]);  // [strip][ql] = 64 floats
  if (ms == 1) {
#pragma unroll
    for (int r = 0; r < 16; ++r) {
      const int ql = (r & 3) + 8 * (r >> 2) + 4 * hi;
      fO[strip * 2048 + ql * 64 + l31] = O0[r];
      fO[strip * 2048 + ql * 64 + 32 + l31] = O1[r];
      if (l31 == 0) fL[strip * 32 + ql] = Ol[r];
    }
  }
  __syncthreads();
  if (ms == 0) {
#pragma unroll
    for (int r = 0; r < 16; ++r) {
      const int ql = (r & 3) + 8 * (r >> 2) + 4 * hi;
      const float o0 = O0[r] + fO[strip * 2048 + ql * 64 + l31];
      const float o1 = O1[r] + fO[strip * 2048 + ql * 64 + 32 + l31];
      const float inv = 1.f / (Ol[r] + fL[strip * 32 + ql]);
      bf16* dst = attnb + ((size_t)(b * 2048 + q0s + ql)) * 1024 + h * 64;
      dst[l31] = (bf16)(o0 * inv);
      dst[32 + l31] = (bf16)(o1 * inv);
    }
  }
}

// ---------------------------------------------------------------------------
extern "C" void kernel_launch(void* const* d_in, const int* in_sizes, int n_in,
                              void* d_out, int out_size, void* d_ws, size_t ws_size,
                              hipStream_t stream) {
  const float* x     = (const float*)d_in[0];  // (2,2048,1024)
  const float* w_qkv = (const float*)d_in[1];  // (1024,3072)
  const float* b_qkv = (const float*)d_in[2];  // (3072)
  const float* w_o   = (const float*)d_in[3];  // (1024,1024)
  const float* b_o   = (const float*)d_in[4];  // (1024)
  float* out = (float*)d_out;                  // (2,2048,1024) fp32

  char* ws = (char*)d_ws;
  bf16* xb    = (bf16*)ws; ws += (size_t)4096 * 1024 * 2;
  bf16* wqkvt = (bf16*)ws; ws += (size_t)3072 * 1024 * 2;
  bf16* wot   = (bf16*)ws; ws += (size_t)1024 * 1024 * 2;
  bf16* qb    = (bf16*)ws; ws += (size_t)32 * 2048 * 64 * 2;
  bf16* kb    = (bf16*)ws; ws += (size_t)32 * 2048 * 64 * 2;
  bf16* vtb   = (bf16*)ws; ws += (size_t)32 * 2048 * 64 * 2;  // (bh,64,S)
  bf16* attnb = (bf16*)ws; ws += (size_t)4096 * 1024 * 2;

  prep_kernel<<<8192, 256, 0, stream>>>(x, xb, w_qkv, wqkvt, w_o, wot);
  gemm_bt_kernel<0, 4><<<dim3(24, 32), 256, 0, stream>>>(
      xb, wqkvt, b_qkv, nullptr, qb, kb, vtb, 3072, 1024);
  attn_kernel<<<1024, 256, 0, stream>>>(qb, kb, vtb, attnb);
  gemm_bt_kernel<1, 2><<<dim3(8, 64), 256, 0, stream>>>(
      attnb, wot, b_o, out, nullptr, nullptr, nullptr, 1024, 1024);
}